// Round 8
// baseline (317.024 us; speedup 1.0000x reference)
//
#include <hip/hip_runtime.h>

#define LOG2E 1.4426950408889634f
#define LN2   0.6931471805599453f

typedef unsigned u32x2 __attribute__((ext_vector_type(2)));

#if __has_builtin(__builtin_amdgcn_permlane16_swap)
#define HAVE_PL16 1
#else
#define HAVE_PL16 0
#endif
#if __has_builtin(__builtin_amdgcn_permlane32_swap)
#define HAVE_PL32 1
#else
#define HAVE_PL32 0
#endif

// Round-8: r7 cut 151->122.6 us by replacing readlane with LDS broadcast, and
// showed dispatch time == longest chain (512 steps x 575 cyc). ~310 cyc/step
// of that is the DS round-trip (write -> 16 in-order ds_read_b128). This
// round removes LDS from the loop entirely: the matvec walks all 64 j via
// in-register windows — quad_perm DPP (xor1/2/3 within quads), row_ror:4
// (across quads in a 16-row), permlane16/32_swap+cndmask (across 16/32,
// VALU) with __shfl_xor fallback. A runtime PROBE replays the identical
// shuffle chain on lane ids and gathers Mreg at the probed indices, making
// the code correct under any DPP direction/polarity convention; swap
// polarity is auto-detected, falling back to shfl if unrecognized.

// quad_perm xor patterns (xor perms are scatter/gather symmetric -> safe).
#define QP_X1 0xB1  // [1,0,3,2]
#define QP_X2 0x4E  // [2,3,0,1]
#define QP_X3 0x1B  // [3,2,1,0]
#define ROR4  0x124 // row_ror:4

template <int CTRL>
__device__ __forceinline__ unsigned dppu(unsigned v) {
  return (unsigned)__builtin_amdgcn_mov_dpp((int)v, CTRL, 0xf, 0xf, true);
}

template <int MODE>  // 0/1: permlane polarity; 2: shfl fallback
__device__ __forceinline__ unsigned xsw16(unsigned v, bool rowodd) {
#if HAVE_PL16
  if (MODE < 2) {
    u32x2 r = __builtin_amdgcn_permlane16_swap(v, v, false, false);
    unsigned cx = MODE ? r.y : r.x;
    unsigned cy = MODE ? r.x : r.y;
    return rowodd ? cx : cy;
  }
#endif
  return (unsigned)__shfl_xor((int)v, 16, 64);
}

template <int MODE>
__device__ __forceinline__ unsigned xsw32(unsigned v, bool hihalf) {
#if HAVE_PL32
  if (MODE < 2) {
    u32x2 r = __builtin_amdgcn_permlane32_swap(v, v, false, false);
    unsigned cx = MODE ? r.y : r.x;
    unsigned cy = MODE ? r.x : r.y;
    return hihalf ? cx : cy;
  }
#endif
  return (unsigned)__shfl_xor((int)v, 32, 64);
}

__device__ __forceinline__ int detect16(int lane) {
#if HAVE_PL16
  bool rowodd = (lane & 16) != 0;
  unsigned t0 = xsw16<0>((unsigned)lane, rowodd);
  if (__ballot(t0 == (unsigned)(lane ^ 16)) == ~0ull) return 0;
  unsigned t1 = xsw16<1>((unsigned)lane, rowodd);
  if (__ballot(t1 == (unsigned)(lane ^ 16)) == ~0ull) return 1;
#endif
  return 2;
}

__device__ __forceinline__ int detect32(int lane) {
#if HAVE_PL32
  bool hihalf = (lane & 32) != 0;
  unsigned t0 = xsw32<0>((unsigned)lane, hihalf);
  if (__ballot(t0 == (unsigned)(lane ^ 32)) == ~0ull) return 0;
  unsigned t1 = xsw32<1>((unsigned)lane, hihalf);
  if (__ballot(t1 == (unsigned)(lane ^ 32)) == ~0ull) return 1;
#endif
  return 2;
}

// Window transition m -> m+1. Sequence: ror4 within each supergroup of 4
// windows; xor16 at window 4 and 12, xor32 at window 8. Covers all 16
// (rot4, x16, x32) quad-offsets exactly once per lane.
template <int NEXT, int M16, int M32>
__device__ __forceinline__ unsigned advanceu(unsigned w, bool rowodd, bool hihalf) {
  if constexpr (NEXT == 4 || NEXT == 12) return xsw16<M16>(w, rowodd);
  else if constexpr (NEXT == 8) return xsw32<M32>(w, hihalf);
  else return dppu<ROR4>(w);
}

template <bool FWD, int M16, int M32>
__device__ __forceinline__ void run_chain(
    const float* __restrict__ hb, const float* __restrict__ trans,
    int lane, int len, int nsteps, float& pOut, int& b2Out) {
  constexpr int N = 64;
  const bool rowodd = (lane & 16) != 0;
  const bool hihalf = (lane & 32) != 0;

  // Probe the shuffle chain on lane ids; gather M (FWD: row lane; BWD:
  // column lane = row of M^T) in exact visit order.
  float Mreg[N];
  {
    unsigned pr = (unsigned)lane;
#pragma unroll
    for (int m = 0; m < 16; ++m) {
      unsigned j0 = pr;
      unsigned j1 = dppu<QP_X1>(pr);
      unsigned j2 = dppu<QP_X2>(pr);
      unsigned j3 = dppu<QP_X3>(pr);
      Mreg[4 * m + 0] = __builtin_amdgcn_exp2f(
          (FWD ? trans[lane * N + j0] : trans[j0 * N + lane]) * LOG2E);
      Mreg[4 * m + 1] = __builtin_amdgcn_exp2f(
          (FWD ? trans[lane * N + j1] : trans[j1 * N + lane]) * LOG2E);
      Mreg[4 * m + 2] = __builtin_amdgcn_exp2f(
          (FWD ? trans[lane * N + j2] : trans[j2 * N + lane]) * LOG2E);
      Mreg[4 * m + 3] = __builtin_amdgcn_exp2f(
          (FWD ? trans[lane * N + j3] : trans[j3 * N + lane]) * LOG2E);
      switch (m + 1) {  // compile-time under unroll
        case 4:  pr = advanceu<4, M16, M32>(pr, rowodd, hihalf); break;
        case 8:  pr = advanceu<8, M16, M32>(pr, rowodd, hihalf); break;
        case 12: pr = advanceu<12, M16, M32>(pr, rowodd, hihalf); break;
        case 16: break;
        default: pr = dppu<ROR4>(pr); break;
      }
    }
  }
  // Pin into arch VGPRs (r2: backend otherwise parks the array in AGPRs).
#pragma unroll
  for (int q = 0; q < 8; ++q) {
    asm volatile("" : "+v"(Mreg[8 * q + 0]), "+v"(Mreg[8 * q + 1]),
                      "+v"(Mreg[8 * q + 2]), "+v"(Mreg[8 * q + 3]),
                      "+v"(Mreg[8 * q + 4]), "+v"(Mreg[8 * q + 5]),
                      "+v"(Mreg[8 * q + 6]), "+v"(Mreg[8 * q + 7]));
  }

  // Init. FWD: alpha_0[i]=exp(h[0,i]+trans[i,START]); BWD: u_END (fold
  // d_{len-1} when there is at least one matvec). START=N-2, END=N-1.
  float p;
  if (FWD) {
    p = __builtin_amdgcn_exp2f((hb[lane] + trans[lane * N + (N - 2)]) * LOG2E);
  } else {
    p = __builtin_amdgcn_exp2f(trans[(N - 1) * N + lane] * LOG2E);
    if (nsteps >= 1)
      p *= __builtin_amdgcn_exp2f(hb[(size_t)(len - 1) * N + lane] * LOG2E);
  }
  int base2 = 0;
  float pend = 1.0f;  // deferred rescale: computed from p_t, applied at t+1
  int pend_b2 = 0;

  const int ns = FWD ? nsteps : nsteps - 1;

  auto step = [&](float D) {
    float mult = D * pend;
    base2 += pend_b2;
    float a[8] = {0.f, 0.f, 0.f, 0.f, 0.f, 0.f, 0.f, 0.f};
    unsigned w = __float_as_uint(p);
#pragma unroll
    for (int m = 0; m < 16; ++m) {
      float f0 = __uint_as_float(w);
      float f1 = __uint_as_float(dppu<QP_X1>(w));
      float f2 = __uint_as_float(dppu<QP_X2>(w));
      float f3 = __uint_as_float(dppu<QP_X3>(w));
      const int c = (4 * m) & 7;
      a[c + 0] = fmaf(Mreg[4 * m + 0], f0, a[c + 0]);
      a[c + 1] = fmaf(Mreg[4 * m + 1], f1, a[c + 1]);
      a[c + 2] = fmaf(Mreg[4 * m + 2], f2, a[c + 2]);
      a[c + 3] = fmaf(Mreg[4 * m + 3], f3, a[c + 3]);
      switch (m + 1) {
        case 4:  w = advanceu<4, M16, M32>(w, rowodd, hihalf); break;
        case 8:  w = advanceu<8, M16, M32>(w, rowodd, hihalf); break;
        case 12: w = advanceu<12, M16, M32>(w, rowodd, hihalf); break;
        case 16: break;
        default: w = dppu<ROR4>(w); break;
      }
    }
    float s = ((a[0] + a[1]) + (a[2] + a[3])) + ((a[4] + a[5]) + (a[6] + a[7]));
    p = s * mult;
    // Deferred anchor rescale (off the serial path; applied next step).
    // p[0] >= max_j p_j * min_j M[0,j] * (D ratio) > 0: bounded slop.
    unsigned bits = (unsigned)__builtin_amdgcn_readfirstlane((int)__float_as_uint(p));
    int e = (int)((bits >> 23) & 0xffu);
    pend_b2 = e - 127;
    pend = __uint_as_float((unsigned)(254 - e) << 23);  // 2^(127-e), exact
  };

  auto emit_of = [&](int s_) -> float {
    int smax = ns < 1 ? 1 : ns;
    int sc = s_ < smax ? s_ : smax;
    if (sc < 1) sc = 1;
    int t = FWD ? sc : (len - 1 - sc);
    if (t < 0) t = 0;  // value unused in these cases; keep address in range
    return __builtin_amdgcn_exp2f(hb[(size_t)t * N + lane] * LOG2E);
  };

  float eb[4];
#pragma unroll
  for (int u = 0; u < 4; ++u) eb[u] = emit_of(1 + u);

  int s = 1;
  for (; s + 4 <= ns + 1; s += 4) {
#pragma unroll
    for (int u = 0; u < 4; ++u) {
      step(eb[u]);
      eb[u] = emit_of(s + u + 4);
    }
  }
  for (; s <= ns; ++s) step(eb[(s - 1) & 3]);  // tail: slot (s-1)&3
  if (!FWD && nsteps >= 1) step(1.0f);         // final raw beta_m step

  pOut = p;
  b2Out = base2;
}

__global__ __launch_bounds__(128)
__attribute__((amdgpu_waves_per_eu(1, 1)))
void crf_fwd_33852932227637(
    const float* __restrict__ h,
    const float* __restrict__ trans,
    const int* __restrict__ lengths,
    float* __restrict__ out,
    int T) {
  constexpr int N = 64;
  const int b = blockIdx.x;
  const int lane = threadIdx.x & 63;
  const int wv = threadIdx.x >> 6;

  const float* hb = h + (size_t)b * T * N;
  const int len = lengths[b];
  const int m = (len - 1) >> 1;  // fwd matvecs: 1..m ; bwd: len-1..m+1

  const int m16 = detect16(lane);
  const int m32 = detect32(lane);

  float p;
  int b2;
#define RUN(M16V, M32V)                                                       \
  do {                                                                        \
    if (wv == 0)                                                              \
      run_chain<true, M16V, M32V>(hb, trans, lane, len, m, p, b2);            \
    else                                                                      \
      run_chain<false, M16V, M32V>(hb, trans, lane, len, len - 1 - m, p, b2); \
  } while (0)

  if (m16 == 0 && m32 == 0)      RUN(0, 0);
  else if (m16 == 1 && m32 == 1) RUN(1, 1);
  else if (m16 == 0 && m32 == 1) RUN(0, 1);
  else if (m16 == 1 && m32 == 0) RUN(1, 0);
  else                           RUN(2, 2);
#undef RUN

  __shared__ float xbeta[N];
  __shared__ int xb2;
  if (wv == 1) {
    xbeta[lane] = p;
    if (lane == 0) xb2 = b2;
  }
  __syncthreads();
  if (wv == 0) {
    // Z * 2^-(b2f+b2b) = sum_i alpha_m[i] * beta_m[i]; anchors keep both
    // factors near 2^0, so the dot neither over- nor underflows.
    float z = p * xbeta[lane];
#pragma unroll
    for (int off = 32; off >= 1; off >>= 1)
      z += __shfl_xor(z, off, 64);
    if (lane == 0)
      out[b] = LN2 * ((float)(b2 + xb2) + __builtin_amdgcn_logf(z));
  }
}

extern "C" void kernel_launch(void* const* d_in, const int* in_sizes, int n_in,
                              void* d_out, int out_size, void* d_ws, size_t ws_size,
                              hipStream_t stream) {
  const float* h = (const float*)d_in[0];
  const float* trans = (const float*)d_in[1];
  const int* lengths = (const int*)d_in[2];
  float* out = (float*)d_out;
  const int B = in_sizes[2];
  const int N = 64;
  const int T = in_sizes[0] / (B * N);
  crf_fwd_33852932227637<<<B, N * 2, 0, stream>>>(h, trans, lengths, out, T);
}